// Round 9
// baseline (79.703 us; speedup 1.0000x reference)
//
#include <hip/hip_runtime.h>
#include <hip/hip_bf16.h>

// Problem constants
#define BATCH   8192
#define NGRP    8
#define MAXGS   64
#define DMODEL  2048
#define TILES   512               // worst-case 16-row tiles per group

typedef __attribute__((ext_vector_type(8))) short  short8;
typedef __attribute__((ext_vector_type(4))) float  f32x4;

#define LISTS_OFF 1024
#define W_OFF (LISTS_OFF + NGRP * BATCH * 4)
#define CNT_STRIDE 16   // ints; 64B line per counter

static __device__ __forceinline__ short bf(float f) {
    __hip_bfloat16 h = __float2bfloat16(f);
    return (short)__bfloat16_as_ushort(h);
}

// Phase 0: zero padded counters + convert W (f32 -> bf16) into ws.
__global__ __launch_bounds__(256) void init_kernel(const float* __restrict__ W,
                                                   unsigned short* __restrict__ Wb,
                                                   int* __restrict__ cnt) {
    int idx = blockIdx.x * 256 + threadIdx.x;
    if (idx < NGRP * CNT_STRIDE) cnt[idx] = 0;
    int e = idx * 4;
    float4 w = *reinterpret_cast<const float4*>(W + e);
    ushort4 o;
    o.x = (unsigned short)bf(w.x); o.y = (unsigned short)bf(w.y);
    o.z = (unsigned short)bf(w.z); o.w = (unsigned short)bf(w.w);
    *reinterpret_cast<ushort4*>(Wb + e) = o;
}

// Phase 1: bucket samples by group (LDS-aggregated atomics; order
// nondeterministic, per-sample output values order-independent).
__global__ __launch_bounds__(256) void bucket_kernel(const int* __restrict__ chosen,
                                                     int* __restrict__ cnt,
                                                     int* __restrict__ lists) {
    __shared__ int lcnt[NGRP];
    __shared__ int lbase[NGRP];
    int tid = threadIdx.x;
    int b = blockIdx.x * 256 + tid;
    int g = chosen[b];
    int lane = tid & 63;
    if (tid < NGRP) lcnt[tid] = 0;
    __syncthreads();

    int wbase = 0;
    unsigned long long mymask = 0;
    #pragma unroll
    for (int gg = 0; gg < NGRP; ++gg) {
        unsigned long long m = __ballot(g == gg);
        if (g == gg) {
            int leader = __ffsll(m) - 1;
            int wb_ = 0;
            if (lane == leader) wb_ = atomicAdd(&lcnt[gg], __popcll(m));
            wb_ = __shfl(wb_, leader);
            wbase = wb_;
            mymask = m;
        }
    }
    __syncthreads();
    if (tid < NGRP) lbase[tid] = atomicAdd(&cnt[tid * CNT_STRIDE], lcnt[tid]);
    __syncthreads();

    int pos = lbase[g] + wbase + __popcll(mymask & ((1ull << lane) - 1ull));
    lists[g * BATCH + pos] = b;
}

// Phase 2: barrier-free direct-gather GEMM.
// WHY (r8 post-mortem): staged designs (LDS ring, producer/consumer, counted
// vmcnt) ALL converge at ~31us = 2.5 TB/s A-supply; phases/barriers and
// shared vmcnt queues were suspects, so this kernel has NONE of them:
// no LDS, no barriers, no cross-wave coupling. 4-wave blocks, waves n-split
// (16 cols each, full K, acc = 1 f32x4). A-frags straight from hidden f32,
// 16B/lane; unroll 8 -> each of the wave's 16 row-streams issues 1KB of
// consecutive cache lines per batch (max DRAM row locality w/o staging).
// B from Wb bf16 (L2-resident per XCD via g=bid&7). 4 blocks/CU, 16 waves/CU
// -> pure-TLP latency hiding, the same regime where fills hit 85% BW.
__global__ __launch_bounds__(256, 4) void gemm_kernel(
    const float* __restrict__ hidden,
    const float* __restrict__ bias,
    const int* __restrict__ gsizes,
    const int* __restrict__ cnt,
    const int* __restrict__ lists,
    const unsigned short* __restrict__ Wb,
    float* __restrict__ out)
{
    int bid = blockIdx.x;
    int g = bid & (NGRP - 1);
    int t = bid >> 3;
    int c = cnt[g * CNT_STRIDE];
    int m0 = t << 4;
    if (m0 >= c) return;           // cheap dead-block exit (no LDS held)

    int tid  = threadIdx.x;
    int cw   = tid >> 6;           // wave id 0..3 -> cols [16cw, 16cw+16)
    int lane = tid & 63;
    int lrow = lane & 15;
    int kg   = lane >> 4;          // 0..3

    int mrow  = m0 + lrow;
    int msafe = mrow < c ? mrow : c - 1;     // tail: dup last row (guarded)
    int smp   = lists[g * BATCH + msafe];

    const float* __restrict__ ap =
        hidden + ((size_t)smp * NGRP + g) * DMODEL + kg * 8;
    const unsigned short* __restrict__ bp =
        Wb + ((size_t)g * MAXGS + cw * 16 + lrow) * DMODEL + kg * 8;

    f32x4 acc = f32x4{0, 0, 0, 0};

    #pragma unroll 8
    for (int ch = 0; ch < DMODEL / 32; ++ch) {
        f32x4 a0 = *reinterpret_cast<const f32x4*>(ap + ch * 32);
        f32x4 a1 = *reinterpret_cast<const f32x4*>(ap + ch * 32 + 4);
        short8 bfr = *reinterpret_cast<const short8*>(bp + ch * 32);
        short8 af;
        af[0] = bf(a0[0]); af[1] = bf(a0[1]); af[2] = bf(a0[2]); af[3] = bf(a0[3]);
        af[4] = bf(a1[0]); af[5] = bf(a1[1]); af[6] = bf(a1[2]); af[7] = bf(a1[3]);
        acc = __builtin_amdgcn_mfma_f32_16x16x32_bf16(af, bfr, acc, 0, 0, 0);
    }

    // epilogue: C col = lrow (our n), row = kg*4 + r (sample in tile)
    int gsz = gsizes[g];
    int n = cw * 16 + lrow;
    float bv = bias[g * MAXGS + n];
    #pragma unroll
    for (int r = 0; r < 4; ++r) {
        int m = m0 + kg * 4 + r;
        if (m < c) {
            int s = lists[g * BATCH + m];
            out[(size_t)s * MAXGS + n] = acc[r] + bv;     // padded n: 0+0 == 0
            out[(size_t)(BATCH + s) * MAXGS + n] = (n < gsz) ? 1.0f : 0.0f;
        }
    }
}

extern "C" void kernel_launch(void* const* d_in, const int* in_sizes, int n_in,
                              void* d_out, int out_size, void* d_ws, size_t ws_size,
                              hipStream_t stream) {
    const float* hidden = (const float*)d_in[0];   // [8192, 8, 2048] f32
    const int*   chosen = (const int*)d_in[1];     // [8192] i32
    const float* W      = (const float*)d_in[2];   // [8, 64, 2048] f32 (zero-padded)
    const float* bias   = (const float*)d_in[3];   // [8, 64] f32 (zero-padded)
    const int*   gs     = (const int*)d_in[4];     // [8] i32
    float* out = (float*)d_out;                    // [8192*64 preds | 8192*64 valid]

    char* ws = (char*)d_ws;
    int* cnt   = (int*)ws;
    int* lists = (int*)(ws + LISTS_OFF);
    unsigned short* Wb = (unsigned short*)(ws + W_OFF);

    init_kernel<<<dim3(1024), dim3(256), 0, stream>>>(W, Wb, cnt);
    bucket_kernel<<<dim3(32), dim3(256), 0, stream>>>(chosen, cnt, lists);
    gemm_kernel<<<dim3(NGRP * TILES), dim3(256), 0, stream>>>(
        hidden, bias, gs, cnt, lists, Wb, out);
}

// Round 10
// 47.222 us; speedup vs baseline: 1.6878x; 1.6878x over previous
//
#include <hip/hip_runtime.h>
#include <hip/hip_bf16.h>

// Problem constants
#define BATCH   8192
#define NGRP    8
#define MAXGS   64
#define DMODEL  2048
#define TM      16                // samples per tile
#define TILES   (BATCH / TM)      // 512 worst-case tiles per group

typedef __attribute__((ext_vector_type(8))) short  short8;
typedef __attribute__((ext_vector_type(4))) float  f32x4;
typedef __attribute__((ext_vector_type(4))) short  short4v;

#define LISTS_OFF 1024
#define W_OFF (LISTS_OFF + NGRP * BATCH * 4)
#define CNT_STRIDE 16   // ints; 64B line per counter

static __device__ __forceinline__ short bf(float f) {
    __hip_bfloat16 h = __float2bfloat16(f);
    return (short)__bfloat16_as_ushort(h);
}

// Phase 0: zero padded counters + convert W (f32 -> bf16) into ws.
__global__ __launch_bounds__(256) void init_kernel(const float* __restrict__ W,
                                                   unsigned short* __restrict__ Wb,
                                                   int* __restrict__ cnt) {
    int idx = blockIdx.x * 256 + threadIdx.x;
    if (idx < NGRP * CNT_STRIDE) cnt[idx] = 0;
    int e = idx * 4;
    float4 w = *reinterpret_cast<const float4*>(W + e);
    ushort4 o;
    o.x = (unsigned short)bf(w.x); o.y = (unsigned short)bf(w.y);
    o.z = (unsigned short)bf(w.z); o.w = (unsigned short)bf(w.w);
    *reinterpret_cast<ushort4*>(Wb + e) = o;
}

// Phase 1: bucket samples by group (LDS-aggregated atomics; order
// nondeterministic, per-sample output values order-independent).
__global__ __launch_bounds__(256) void bucket_kernel(const int* __restrict__ chosen,
                                                     int* __restrict__ cnt,
                                                     int* __restrict__ lists) {
    __shared__ int lcnt[NGRP];
    __shared__ int lbase[NGRP];
    int tid = threadIdx.x;
    int b = blockIdx.x * 256 + tid;
    int g = chosen[b];
    int lane = tid & 63;
    if (tid < NGRP) lcnt[tid] = 0;
    __syncthreads();

    int wbase = 0;
    unsigned long long mymask = 0;
    #pragma unroll
    for (int gg = 0; gg < NGRP; ++gg) {
        unsigned long long m = __ballot(g == gg);
        if (g == gg) {
            int leader = __ffsll(m) - 1;
            int wb_ = 0;
            if (lane == leader) wb_ = atomicAdd(&lcnt[gg], __popcll(m));
            wb_ = __shfl(wb_, leader);
            wbase = wb_;
            mymask = m;
        }
    }
    __syncthreads();
    if (tid < NGRP) lbase[tid] = atomicAdd(&cnt[tid * CNT_STRIDE], lcnt[tid]);
    __syncthreads();

    int pos = lbase[g] + wbase + __popcll(mymask & ((1ull << lane) - 1ull));
    lists[g * BATCH + pos] = b;
}

// Phase 2: single-stage GEMM with FULL-ROW burst staging.
// WHY (r4-r9 post-mortems): all phased/staged designs visit each 8KB A-row
// in 4-16 separate 0.5-2KB slices -> ~2.5 TB/s gather rate with every pipe
// idle. Here each row is visited ONCE as 8 back-to-back 1KB loads (8KB
// contiguous burst), converted f32->bf16 in-reg, ds_written swizzled; whole
// K then sits in 64KB LDS -> ONE barrier, no phases, no ring. B-loads (L2
// Wb) can no longer pollute the A queue (A is done before the barrier).
// Swizzle byte ^= ((r&7)<<4)|((r&1)<<6): read 2-way max (free), write clean.
__global__ __launch_bounds__(256, 2) void gemm_kernel(
    const float* __restrict__ hidden,
    const float* __restrict__ bias,
    const int* __restrict__ gsizes,
    const int* __restrict__ cnt,
    const int* __restrict__ lists,
    const unsigned short* __restrict__ Wb,
    float* __restrict__ out)
{
    int bid = blockIdx.x;
    int g = bid & (NGRP - 1);      // group <-> XCD alignment: Wb L2-resident
    int t = bid >> 3;
    int c = cnt[g * CNT_STRIDE];
    int m0 = t * TM;
    if (m0 >= c) return;           // uniform dead-block exit

    __shared__ unsigned short A[TM][DMODEL];   // bf16, 64 KB

    int tid  = threadIdx.x;
    int w    = tid >> 6;           // wave 0..3
    int lane = tid & 63;
    int lrow = lane & 15;
    int kg   = lane >> 4;          // 0..3

    // ---- stage: wave w owns rows 4w..4w+3; each row = one 8KB burst ----
    {
        const float* src[4];
        #pragma unroll
        for (int i = 0; i < 4; ++i) {
            int m  = m0 + 4 * w + i;
            int ms = m < c ? m : c - 1;          // tail: dup last row (guarded)
            src[i] = hidden + ((size_t)lists[g * BATCH + ms] * NGRP + g) * DMODEL
                   + lane * 4;
        }
        // software pipeline: rows i and i+1 in flight (16KB/wave outstanding)
        f32x4 ra[8], rb[8];
        #pragma unroll
        for (int h = 0; h < 8; ++h)
            ra[h] = *reinterpret_cast<const f32x4*>(src[0] + h * 256);
        #pragma unroll
        for (int h = 0; h < 8; ++h)
            rb[h] = *reinterpret_cast<const f32x4*>(src[1] + h * 256);

        #pragma unroll
        for (int i = 0; i < 4; ++i) {
            int r = 4 * w + i;
            int swz = ((r & 7) << 4) | ((r & 1) << 6);
            char* abase = (char*)&A[r][0];
            #pragma unroll
            for (int h = 0; h < 8; ++h) {
                f32x4 v = ra[h];
                short4v o;
                o[0] = bf(v[0]); o[1] = bf(v[1]); o[2] = bf(v[2]); o[3] = bf(v[3]);
                int byte = (h * 512 + lane * 8) ^ swz;
                *reinterpret_cast<short4v*>(abase + byte) = o;
            }
            // rotate pipeline: move rb -> ra, issue next row into rb
            if (i < 3) {
                #pragma unroll
                for (int h = 0; h < 8; ++h) ra[h] = rb[h];
                if (i < 2) {
                    #pragma unroll
                    for (int h = 0; h < 8; ++h)
                        rb[h] = *reinterpret_cast<const f32x4*>(src[i + 2] + h * 256);
                }
            }
        }
    }
    __syncthreads();

    // ---- compute: wave w owns cols [16w, 16w+16), full K from LDS ----
    {
        int swzr = ((lrow & 7) << 4) | ((lrow & 1) << 6);
        const char* arow = (const char*)&A[lrow][0];
        const unsigned short* bp =
            Wb + ((size_t)g * MAXGS + w * 16 + lrow) * DMODEL + kg * 8;

        f32x4 acc = f32x4{0, 0, 0, 0};
        #pragma unroll 8
        for (int kk = 0; kk < DMODEL / 32; ++kk) {
            int byte = (kk * 64 + kg * 16) ^ swzr;
            short8 af = *reinterpret_cast<const short8*>(arow + byte);
            short8 bfr = *reinterpret_cast<const short8*>(bp + kk * 32);
            acc = __builtin_amdgcn_mfma_f32_16x16x32_bf16(af, bfr, acc, 0, 0, 0);
        }

        // epilogue: C col = lrow (n), row = kg*4 + r (sample in tile)
        int gsz = gsizes[g];
        int n = w * 16 + lrow;
        float bv = bias[g * MAXGS + n];
        #pragma unroll
        for (int r = 0; r < 4; ++r) {
            int m = m0 + kg * 4 + r;
            if (m < c) {
                int s = lists[g * BATCH + m];
                out[(size_t)s * MAXGS + n] = acc[r] + bv;   // padded n: 0+0 == 0
                out[(size_t)(BATCH + s) * MAXGS + n] = (n < gsz) ? 1.0f : 0.0f;
            }
        }
    }
}

extern "C" void kernel_launch(void* const* d_in, const int* in_sizes, int n_in,
                              void* d_out, int out_size, void* d_ws, size_t ws_size,
                              hipStream_t stream) {
    const float* hidden = (const float*)d_in[0];   // [8192, 8, 2048] f32
    const int*   chosen = (const int*)d_in[1];     // [8192] i32
    const float* W      = (const float*)d_in[2];   // [8, 64, 2048] f32 (zero-padded)
    const float* bias   = (const float*)d_in[3];   // [8, 64] f32 (zero-padded)
    const int*   gs     = (const int*)d_in[4];     // [8] i32
    float* out = (float*)d_out;                    // [8192*64 preds | 8192*64 valid]

    char* ws = (char*)d_ws;
    int* cnt   = (int*)ws;
    int* lists = (int*)(ws + LISTS_OFF);
    unsigned short* Wb = (unsigned short*)(ws + W_OFF);

    init_kernel<<<dim3(1024), dim3(256), 0, stream>>>(W, Wb, cnt);
    bucket_kernel<<<dim3(32), dim3(256), 0, stream>>>(chosen, cnt, lists);
    gemm_kernel<<<dim3(NGRP * TILES), dim3(256), 0, stream>>>(
        hidden, bias, gs, cnt, lists, Wb, out);
}